// Round 6
// baseline (330.519 us; speedup 1.0000x reference)
//
#include <hip/hip_runtime.h>
#include <hip/hip_bf16.h>

// Problem: CrossViewFusionModule  (see reference in earlier rounds)
//   outputs: (context [16,256,128,128], attn [16,1,128,128]) concat in d_out.
//
// R6: single persistent fused kernel, 256 blocks (1 per CU). Batches b=0..15
// processed sequentially by ALL blocks; each block owns a fixed 64-wh slice.
// Per b: score slice (score/invn stay in LDS), per-b atomicMin/Max + release
// counter; software-pipelined so score(b+1) runs before waiting on cnt(b) ->
// barrier hidden; ctx(b) then re-reads the slice (L2/L3-hot: 2.1 MB/XCD,
// 16.75 MB/L3) and nt-stores ctx+attn. HBM traffic ~805 -> ~540 MB.

#define B_   16
#define D_   256
#define WH_  16384   // 128*128
#define NBLK 256     // == CU count; 1 block/CU, co-resident
#define WPB  64      // wh floats per block (NBLK*WPB == WH_)

// ---- monotone float <-> sortable uint mapping (exact atomic min/max) ----
__device__ __forceinline__ unsigned int fmap(float f) {
    unsigned int u = __float_as_uint(f);
    return (u & 0x80000000u) ? ~u : (u | 0x80000000u);
}
__device__ __forceinline__ float funmap(unsigned int u) {
    unsigned int b = (u & 0x80000000u) ? (u ^ 0x80000000u) : ~u;
    return __uint_as_float(b);
}

typedef float f32x4_t __attribute__((ext_vector_type(4)));
__device__ __forceinline__ void nt_store4(float* p, float4 v) {
    f32x4_t w = {v.x, v.y, v.z, v.w};
    __builtin_nontemporal_store(w, (f32x4_t*)p);
}

__global__ void init_kernel(unsigned int* __restrict__ mm,
                            unsigned int* __restrict__ cnt) {
    int i = threadIdx.x;
    if (i < 2 * B_) mm[i] = (i & 1) ? 0u : 0xFFFFFFFFu;  // even: min, odd: max
    if (i < B_) cnt[i] = 0u;
}

// grid = (NBLK), block = 256. tid: col = tid&15 (float4 col of the 64-wh
// slice), dgrp = tid>>4 (owns d = dgrp*16 .. dgrp*16+15).
__global__ __launch_bounds__(256) void fused_kernel(
    const float* __restrict__ q, const float* __restrict__ value,
    unsigned int* __restrict__ mm, unsigned int* __restrict__ cnt,
    float* __restrict__ out_ctx, float* __restrict__ out_attn)
{
    const int tid  = threadIdx.x;
    const int col  = tid & 15;
    const int dgrp = tid >> 4;
    const int whb  = blockIdx.x * WPB;

    __shared__ float qs[D_];
    __shared__ float red[256];
    __shared__ float part[16][16][9];       // [dgrp][col][8 vals + pad]
    __shared__ float scL[2][WPB], ivL[2][WPB];   // double-buffered (pipeline)
    __shared__ float bmn_s, bsc_s;

    const size_t slice_off = (size_t)whb + (size_t)col * 4;

    for (int b = 0; b < B_; ++b) {
        const int pb = b & 1;
        // ---------------- score(b) ----------------
        // q-row normalize (all 256 threads)
        float qv = q[b * D_ + tid];
        red[tid] = qv * qv;
        __syncthreads();
        for (int s = 128; s > 0; s >>= 1) {
            if (tid < s) red[tid] += red[tid + s];
            __syncthreads();
        }
        float qinv = 1.0f / fmaxf(sqrtf(red[0]), 1e-12f);
        __syncthreads();
        qs[tid] = qv * qinv;
        __syncthreads();

        // partial reduce: 16 d-rows, one float4 col
        const float* vb = value + ((size_t)b * D_ + dgrp * 16) * WH_ + slice_off;
        float ss0 = 0.f, ss1 = 0.f, ss2 = 0.f, ss3 = 0.f;
        float dt0 = 0.f, dt1 = 0.f, dt2 = 0.f, dt3 = 0.f;
#pragma unroll
        for (int k = 0; k < 16; ++k) {
            float4 v4 = *(const float4*)(vb + (size_t)k * WH_);
            float qd = qs[dgrp * 16 + k];
            ss0 += v4.x * v4.x; ss1 += v4.y * v4.y;
            ss2 += v4.z * v4.z; ss3 += v4.w * v4.w;
            dt0 += qd * v4.x;   dt1 += qd * v4.y;
            dt2 += qd * v4.z;   dt3 += qd * v4.w;
        }
        float* p = &part[dgrp][col][0];
        p[0] = ss0; p[1] = ss1; p[2] = ss2; p[3] = ss3;
        p[4] = dt0; p[5] = dt1; p[6] = dt2; p[7] = dt3;
        __syncthreads();
        for (int s = 8; s >= 1; s >>= 1) {
            if (dgrp < s) {
#pragma unroll
                for (int j = 0; j < 8; ++j)
                    part[dgrp][col][j] += part[dgrp + s][col][j];
            }
            __syncthreads();
        }
        if (tid < 16) {   // dgrp==0, col==tid: finalize 4 wh
            const float* t8 = &part[0][tid][0];
            float n0 = 1.0f / fmaxf(sqrtf(t8[0]), 1e-12f);
            float n1 = 1.0f / fmaxf(sqrtf(t8[1]), 1e-12f);
            float n2 = 1.0f / fmaxf(sqrtf(t8[2]), 1e-12f);
            float n3 = 1.0f / fmaxf(sqrtf(t8[3]), 1e-12f);
            float s0 = t8[4] * n0, s1 = t8[5] * n1;
            float s2 = t8[6] * n2, s3 = t8[7] * n3;
            scL[pb][tid * 4 + 0] = s0; ivL[pb][tid * 4 + 0] = n0;
            scL[pb][tid * 4 + 1] = s1; ivL[pb][tid * 4 + 1] = n1;
            scL[pb][tid * 4 + 2] = s2; ivL[pb][tid * 4 + 2] = n2;
            scL[pb][tid * 4 + 3] = s3; ivL[pb][tid * 4 + 3] = n3;
            red[tid]      = fminf(fminf(s0, s1), fminf(s2, s3));
            red[16 + tid] = fmaxf(fmaxf(s0, s1), fmaxf(s2, s3));
        }
        __syncthreads();
        if (tid == 0) {
            float mn = red[0], mx = red[16];
            for (int i = 1; i < 16; ++i) {
                mn = fminf(mn, red[i]); mx = fmaxf(mx, red[16 + i]);
            }
            atomicMin(&mm[2 * b],     fmap(mn));
            atomicMax(&mm[2 * b + 1], fmap(mx));
            __hip_atomic_fetch_add(&cnt[b], 1u, __ATOMIC_ACQ_REL,
                                   __HIP_MEMORY_SCOPE_AGENT);   // arrive(b)
        }

        // ---------------- ctx(b-1): barrier hidden behind score(b) ----------
        if (b > 0) {
            const int c  = b - 1;
            const int pc = c & 1;
            if (tid == 0) {
                while (__hip_atomic_load(&cnt[c], __ATOMIC_ACQUIRE,
                                         __HIP_MEMORY_SCOPE_AGENT) < NBLK)
                    __builtin_amdgcn_s_sleep(2);
                unsigned um = __hip_atomic_load(&mm[2 * c], __ATOMIC_ACQUIRE,
                                                __HIP_MEMORY_SCOPE_AGENT);
                unsigned ux = __hip_atomic_load(&mm[2 * c + 1], __ATOMIC_ACQUIRE,
                                                __HIP_MEMORY_SCOPE_AGENT);
                float mnv = funmap(um);
                bmn_s = mnv;
                bsc_s = 1.0f / (funmap(ux) - mnv + 1e-8f);
            }
            __syncthreads();
            float mnv = bmn_s, scv = bsc_s;
            float a0 = (scL[pc][col * 4 + 0] - mnv) * scv;
            float a1 = (scL[pc][col * 4 + 1] - mnv) * scv;
            float a2 = (scL[pc][col * 4 + 2] - mnv) * scv;
            float a3 = (scL[pc][col * 4 + 3] - mnv) * scv;
            if (tid < 16)
                nt_store4(out_attn + (size_t)c * WH_ + whb + tid * 4,
                          make_float4(a0, a1, a2, a3));
            float an0 = a0 * ivL[pc][col * 4 + 0];
            float an1 = a1 * ivL[pc][col * 4 + 1];
            float an2 = a2 * ivL[pc][col * 4 + 2];
            float an3 = a3 * ivL[pc][col * 4 + 3];
            const float* vc = value   + ((size_t)c * D_ + dgrp * 16) * WH_ + slice_off;
            float*       oc = out_ctx + ((size_t)c * D_ + dgrp * 16) * WH_ + slice_off;
#pragma unroll
            for (int k = 0; k < 16; ++k) {
                float4 v4 = *(const float4*)(vc + (size_t)k * WH_);
                float4 c4;
                c4.x = an0 * v4.x; c4.y = an1 * v4.y;
                c4.z = an2 * v4.z; c4.w = an3 * v4.w;
                nt_store4(oc + (size_t)k * WH_, c4);
            }
            __syncthreads();   // protect scL/ivL[pc] before score(b+1) reuses it
        }
    }

    // ---------------- ctx(15): trailing ----------------
    {
        const int c = B_ - 1, pc = c & 1;
        if (tid == 0) {
            while (__hip_atomic_load(&cnt[c], __ATOMIC_ACQUIRE,
                                     __HIP_MEMORY_SCOPE_AGENT) < NBLK)
                __builtin_amdgcn_s_sleep(2);
            unsigned um = __hip_atomic_load(&mm[2 * c], __ATOMIC_ACQUIRE,
                                            __HIP_MEMORY_SCOPE_AGENT);
            unsigned ux = __hip_atomic_load(&mm[2 * c + 1], __ATOMIC_ACQUIRE,
                                            __HIP_MEMORY_SCOPE_AGENT);
            float mnv = funmap(um);
            bmn_s = mnv;
            bsc_s = 1.0f / (funmap(ux) - mnv + 1e-8f);
        }
        __syncthreads();
        float mnv = bmn_s, scv = bsc_s;
        float a0 = (scL[pc][col * 4 + 0] - mnv) * scv;
        float a1 = (scL[pc][col * 4 + 1] - mnv) * scv;
        float a2 = (scL[pc][col * 4 + 2] - mnv) * scv;
        float a3 = (scL[pc][col * 4 + 3] - mnv) * scv;
        if (tid < 16)
            nt_store4(out_attn + (size_t)c * WH_ + whb + tid * 4,
                      make_float4(a0, a1, a2, a3));
        float an0 = a0 * ivL[pc][col * 4 + 0];
        float an1 = a1 * ivL[pc][col * 4 + 1];
        float an2 = a2 * ivL[pc][col * 4 + 2];
        float an3 = a3 * ivL[pc][col * 4 + 3];
        const float* vc = value   + ((size_t)c * D_ + dgrp * 16) * WH_ + slice_off;
        float*       oc = out_ctx + ((size_t)c * D_ + dgrp * 16) * WH_ + slice_off;
#pragma unroll
        for (int k = 0; k < 16; ++k) {
            float4 v4 = *(const float4*)(vc + (size_t)k * WH_);
            float4 c4;
            c4.x = an0 * v4.x; c4.y = an1 * v4.y;
            c4.z = an2 * v4.z; c4.w = an3 * v4.w;
            nt_store4(oc + (size_t)k * WH_, c4);
        }
    }
}

extern "C" void kernel_launch(void* const* d_in, const int* in_sizes, int n_in,
                              void* d_out, int out_size, void* d_ws, size_t ws_size,
                              hipStream_t stream) {
    const float* q     = (const float*)d_in[0];   // [16,256]
    const float* value = (const float*)d_in[1];   // [16,256,128,128]

    float* out_ctx  = (float*)d_out;                       // B*D*WH floats
    float* out_attn = out_ctx + (size_t)B_ * D_ * WH_;     // B*WH floats

    // workspace: mm [2*B] u32 | cnt [B] u32
    unsigned int* mm  = (unsigned int*)d_ws;
    unsigned int* cnt = mm + 2 * B_;

    hipLaunchKernelGGL(init_kernel, dim3(1), dim3(64), 0, stream, mm, cnt);
    hipLaunchKernelGGL(fused_kernel, dim3(NBLK), dim3(256), 0, stream,
                       q, value, mm, cnt, out_ctx, out_attn);
}

// Round 7
// 130.268 us; speedup vs baseline: 2.5372x; 2.5372x over previous
//
#include <hip/hip_runtime.h>
#include <hip/hip_bf16.h>

// Problem: CrossViewFusionModule
//   global_query: [B=16, D=256] f32
//   value:        [B=16, D=256, W=128, H=128] f32
//   q = l2norm(q, axis=-1); v = l2norm(value, axis=D)
//   score[b,wh] = sum_d q[b,d]*v[b,d,wh]
//   attn = (score - min_b) / (max_b - min_b + 1e-8)   (min/max over wh per b)
//   context = attn * v
//   outputs: (context [B,D,W,H], attn [B,1,W,H]) concat in d_out.
//
// R7: score EXACTLY R3 (champion). ctx rewritten as a TRUE LRU mirror:
// 256 blocks, same (x,b) slice partition as score, each block walks its
// slice's full d-range DESCENDING (time-reverse of score's ascending sweep)
// so the L3's most-recently-cached value lines are consumed first.
// nt stores keep the 269 MB output stream from evicting value.

#define B_  16
#define D_  256
#define WH_ 16384   // 128*128

// ---- monotone float <-> sortable uint mapping (for exact atomic min/max) ----
__device__ __forceinline__ unsigned int fmap(float f) {
    unsigned int u = __float_as_uint(f);
    return (u & 0x80000000u) ? ~u : (u | 0x80000000u);
}
__device__ __forceinline__ float funmap(unsigned int u) {
    unsigned int b = (u & 0x80000000u) ? (u ^ 0x80000000u) : ~u;
    return __uint_as_float(b);
}

typedef float f32x4_t __attribute__((ext_vector_type(4)));
__device__ __forceinline__ void nt_store4(float* p, float4 v) {
    f32x4_t w = {v.x, v.y, v.z, v.w};
    __builtin_nontemporal_store(w, (f32x4_t*)p);   // global_store_dwordx4 ... nt
}

__global__ void init_mm_kernel(unsigned int* __restrict__ mm) {
    int i = threadIdx.x;
    if (i < 2 * B_) mm[i] = (i & 1) ? 0u : 0xFFFFFFFFu;  // even: min, odd: max
}

// One block = 1024 contiguous wh positions of one b (256 threads x float4).
// grid = (WH/1024, B). d ascends 0..255 (defines the L3 recency order).
__global__ __launch_bounds__(256) void score_kernel(
    const float* __restrict__ q, const float* __restrict__ value,
    float* __restrict__ score, float* __restrict__ invn,
    unsigned int* __restrict__ mm)
{
    const int b   = blockIdx.y;
    const int tid = threadIdx.x;
    __shared__ float qs[D_];
    __shared__ float red[256];

    // ---- normalize q row in LDS ----
    float qv = q[b * D_ + tid];
    red[tid] = qv * qv;
    __syncthreads();
    for (int s = 128; s > 0; s >>= 1) {
        if (tid < s) red[tid] += red[tid + s];
        __syncthreads();
    }
    float qnorm2 = red[0];
    __syncthreads();
    qs[tid] = qv * (1.0f / fmaxf(sqrtf(qnorm2), 1e-12f));
    __syncthreads();

    // ---- per-thread: 4 wh columns, reduce over D ----
    const int wh0 = (blockIdx.x * 256 + tid) * 4;
    const float* vb = value + (size_t)b * D_ * WH_ + wh0;
    float ss0 = 0.f, ss1 = 0.f, ss2 = 0.f, ss3 = 0.f;
    float dt0 = 0.f, dt1 = 0.f, dt2 = 0.f, dt3 = 0.f;
#pragma unroll 4
    for (int d = 0; d < D_; ++d) {
        float4 v4 = *(const float4*)(vb + (size_t)d * WH_);
        float qd = qs[d];
        ss0 += v4.x * v4.x; ss1 += v4.y * v4.y;
        ss2 += v4.z * v4.z; ss3 += v4.w * v4.w;
        dt0 += qd * v4.x;   dt1 += qd * v4.y;
        dt2 += qd * v4.z;   dt3 += qd * v4.w;
    }
    float n0 = 1.0f / fmaxf(sqrtf(ss0), 1e-12f);
    float n1 = 1.0f / fmaxf(sqrtf(ss1), 1e-12f);
    float n2 = 1.0f / fmaxf(sqrtf(ss2), 1e-12f);
    float n3 = 1.0f / fmaxf(sqrtf(ss3), 1e-12f);
    float s0 = dt0 * n0, s1 = dt1 * n1, s2 = dt2 * n2, s3 = dt3 * n3;

    *(float4*)(score + (size_t)b * WH_ + wh0) = make_float4(s0, s1, s2, s3);
    *(float4*)(invn  + (size_t)b * WH_ + wh0) = make_float4(n0, n1, n2, n3);

    // ---- block min/max -> one atomic pair per block ----
    float mn = fminf(fminf(s0, s1), fminf(s2, s3));
    float mx = fmaxf(fmaxf(s0, s1), fmaxf(s2, s3));
    red[tid] = mn;
    __syncthreads();
    for (int s = 128; s > 0; s >>= 1) {
        if (tid < s) red[tid] = fminf(red[tid], red[tid + s]);
        __syncthreads();
    }
    float bmn = red[0];
    __syncthreads();
    red[tid] = mx;
    __syncthreads();
    for (int s = 128; s > 0; s >>= 1) {
        if (tid < s) red[tid] = fmaxf(red[tid], red[tid + s]);
        __syncthreads();
    }
    if (tid == 0) {
        atomicMin(&mm[2 * b],     fmap(bmn));
        atomicMax(&mm[2 * b + 1], fmap(red[0]));
    }
}

// TRUE-mirror elementwise pass. grid = (WH/1024, B), block = 256 — the SAME
// (x,b) slice partition as score_kernel, one block per CU. Each block walks
// its slice d = 255..0 (exact time-reverse of score) so the newest L3 lines
// are consumed first and the sweep moves backward through cache recency.
__global__ __launch_bounds__(256) void ctx_kernel(
    const float* __restrict__ value, const float* __restrict__ score,
    const float* __restrict__ invn, const unsigned int* __restrict__ mm,
    float* __restrict__ out_ctx, float* __restrict__ out_attn)
{
    const int b   = blockIdx.y;
    const int wh0 = (blockIdx.x * 256 + threadIdx.x) * 4;

    const float mn = funmap(mm[2 * b]);
    const float sc = 1.0f / (funmap(mm[2 * b + 1]) - mn + 1e-8f);

    float4 s4 = *(const float4*)(score + (size_t)b * WH_ + wh0);
    float4 n4 = *(const float4*)(invn  + (size_t)b * WH_ + wh0);
    float4 a4;
    a4.x = (s4.x - mn) * sc; a4.y = (s4.y - mn) * sc;
    a4.z = (s4.z - mn) * sc; a4.w = (s4.w - mn) * sc;
    nt_store4(out_attn + (size_t)b * WH_ + wh0, a4);   // once per slice-thread

    const float an0 = a4.x * n4.x, an1 = a4.y * n4.y;
    const float an2 = a4.z * n4.z, an3 = a4.w * n4.w;

    const float* vb = value   + (size_t)b * D_ * WH_ + wh0;
    float*       cb = out_ctx + (size_t)b * D_ * WH_ + wh0;
#pragma unroll 8
    for (int d = D_ - 1; d >= 0; --d) {
        float4 v4 = *(const float4*)(vb + (size_t)d * WH_);
        float4 c4;
        c4.x = an0 * v4.x; c4.y = an1 * v4.y;
        c4.z = an2 * v4.z; c4.w = an3 * v4.w;
        nt_store4(cb + (size_t)d * WH_, c4);
    }
}

extern "C" void kernel_launch(void* const* d_in, const int* in_sizes, int n_in,
                              void* d_out, int out_size, void* d_ws, size_t ws_size,
                              hipStream_t stream) {
    const float* q     = (const float*)d_in[0];   // [16,256]
    const float* value = (const float*)d_in[1];   // [16,256,128,128]

    float* out_ctx  = (float*)d_out;                       // B*D*WH floats
    float* out_attn = out_ctx + (size_t)B_ * D_ * WH_;     // B*WH floats

    // workspace: score [B*WH] f32 | invn [B*WH] f32 | mm [2*B] u32  (~2.1 MB)
    float* score = (float*)d_ws;
    float* invn  = score + (size_t)B_ * WH_;
    unsigned int* mm = (unsigned int*)(invn + (size_t)B_ * WH_);

    hipLaunchKernelGGL(init_mm_kernel, dim3(1), dim3(64), 0, stream, mm);
    hipLaunchKernelGGL(score_kernel, dim3(WH_ / 1024, B_), dim3(256), 0, stream,
                       q, value, score, invn, mm);
    hipLaunchKernelGGL(ctx_kernel, dim3(WH_ / 1024, B_), dim3(256),
                       0, stream, value, score, invn, mm, out_ctx, out_attn);
}